// Round 3
// baseline (139.726 us; speedup 1.0000x reference)
//
#include <hip/hip_runtime.h>
#include <hip/hip_bf16.h>
#include <stdint.h>

typedef __attribute__((ext_vector_type(8))) short short8;
typedef __attribute__((ext_vector_type(4))) float float4_t;

#define DDIM 128
#define SORTN 256
#define TCAP 2048   // max packed tokens (input: T=2048)
#define NCH  32     // max chunks of 64 positions per token

__device__ inline unsigned short f32_to_bf16_rne(float f) {
    uint32_t u = __float_as_uint(f);
    return (unsigned short)((u + 0x7FFFu + ((u >> 16) & 1u)) >> 16);
}
__device__ inline float bf16_to_f32(unsigned short h) {
    return __uint_as_float(((uint32_t)h) << 16);
}

// ---- rotate k: one wave per row, FWHT-128 via registers + shfl, no LDS ----
__global__ __launch_bounds__(256) void rotate_k_kernel(
        const unsigned short* __restrict__ k, unsigned short* __restrict__ kr, int T) {
    int row = blockIdx.x * 4 + (threadIdx.x >> 6);
    if (row >= T) return;
    int lane = threadIdx.x & 63;
    ushort2 in = *(const ushort2*)(k + (size_t)row * DDIM + 2 * lane);
    float x0 = bf16_to_f32(in.x), x1 = bf16_to_f32(in.y);
    { float a = x0 + x1, b = x0 - x1; x0 = a; x1 = b; }
    #pragma unroll
    for (int m = 1; m <= 32; m <<= 1) {
        float y0 = __shfl_xor(x0, m, 64);
        float y1 = __shfl_xor(x1, m, 64);
        bool hi = (lane & m) != 0;
        x0 = hi ? (y0 - x0) : (x0 + y0);
        x1 = hi ? (y1 - x1) : (x1 + y1);
    }
    const float sc = 0.08838834764831845f;
    ushort2 o; o.x = f32_to_bf16_rne(x0 * sc); o.y = f32_to_bf16_rne(x1 * sc);
    *(ushort2*)(kr + (size_t)row * DDIM + 2 * lane) = o;
}

__device__ inline void do_tile(int s0, int ke, int ks, int T, int lane, int col, int kgrp,
                               const unsigned short* __restrict__ kr,
                               const short8* afrag, const float* w4,
                               float* scoresL) {
    int sa = s0 + col; if (sa >= T) sa = T - 1;            // clamp pad rows (masked below)
    const short8* kb = (const short8*)(kr + (size_t)sa * DDIM + kgrp * 8);
    float4_t acc = {0.f, 0.f, 0.f, 0.f};
    acc = __builtin_amdgcn_mfma_f32_16x16x32_bf16(afrag[0], kb[0],  acc, 0, 0, 0);
    acc = __builtin_amdgcn_mfma_f32_16x16x32_bf16(afrag[1], kb[4],  acc, 0, 0, 0);
    acc = __builtin_amdgcn_mfma_f32_16x16x32_bf16(afrag[2], kb[8],  acc, 0, 0, 0);
    acc = __builtin_amdgcn_mfma_f32_16x16x32_bf16(afrag[3], kb[12], acc, 0, 0, 0);
    float p = 0.f;
    #pragma unroll
    for (int r = 0; r < 4; ++r) { float v = acc[r]; v = v > 0.f ? v : 0.f; p += w4[r] * v; }
    p += __shfl_xor(p, 16, 64);
    p += __shfl_xor(p, 32, 64);
    if (lane < 16) { int s = s0 + lane; if (s < ke) scoresL[s - ks] = p; }
}

// one wave (64 threads) per token
__global__ __launch_bounds__(64) void indexer_main(
        const unsigned short* __restrict__ q,   // [T,H,128] bf16 bits
        const float* __restrict__ w,            // [T,H]
        const int* __restrict__ seq_lens, int n_seq,
        const unsigned short* __restrict__ kr,  // [T,128] rotated bf16 bits
        float* __restrict__ out_vals, float* __restrict__ out_idx,
        int T, int H, int K) {
    __shared__ float scoresL[TCAP];                 // 8 KB
    __shared__ unsigned long long cand[SORTN];      // 2 KB

    const int t    = T - 1 - blockIdx.x;            // big-n tokens first
    const int lane = threadIdx.x;
    const int col  = lane & 15;
    const int kgrp = lane >> 4;

    int ks = 0;
    { int off = 0;
      for (int i = 0; i < n_seq; ++i) { int nx = off + seq_lens[i]; if (t < nx) { ks = off; break; } off = nx; } }
    const int ke = t + 1;
    const int n  = ke - ks;

    // ---- rotate q[t] in registers: f[kk][j] = qrow[col][kk*32 + kgrp*8 + j] ----
    float f[4][8];
    const unsigned short* qrow = q + ((size_t)t * H + col) * DDIM + kgrp * 8;
    #pragma unroll
    for (int kk = 0; kk < 4; ++kk) {
        short8 v = *(const short8*)(qrow + kk * 32);
        #pragma unroll
        for (int j = 0; j < 8; ++j) f[kk][j] = bf16_to_f32((unsigned short)v[j]);
    }
    #pragma unroll
    for (int b = 1; b <= 4; b <<= 1)
        #pragma unroll
        for (int kk = 0; kk < 4; ++kk)
            #pragma unroll
            for (int j = 0; j < 8; ++j)
                if (!(j & b)) { float a = f[kk][j], c = f[kk][j | b];
                                f[kk][j] = a + c; f[kk][j | b] = a - c; }
    #pragma unroll
    for (int kk = 0; kk < 4; ++kk)
        #pragma unroll
        for (int j = 0; j < 8; ++j) {
            float o = __shfl_xor(f[kk][j], 16, 64);
            f[kk][j] = (kgrp & 1) ? (o - f[kk][j]) : (f[kk][j] + o);
        }
    #pragma unroll
    for (int kk = 0; kk < 4; ++kk)
        #pragma unroll
        for (int j = 0; j < 8; ++j) {
            float o = __shfl_xor(f[kk][j], 32, 64);
            f[kk][j] = (kgrp & 2) ? (o - f[kk][j]) : (f[kk][j] + o);
        }
    #pragma unroll
    for (int j = 0; j < 8; ++j) {
        { float a = f[0][j], c = f[1][j]; f[0][j] = a + c; f[1][j] = a - c; }
        { float a = f[2][j], c = f[3][j]; f[2][j] = a + c; f[3][j] = a - c; }
        { float a = f[0][j], c = f[2][j]; f[0][j] = a + c; f[2][j] = a - c; }
        { float a = f[1][j], c = f[3][j]; f[1][j] = a + c; f[3][j] = a - c; }
    }
    short8 afrag[4];
    const float sc = 0.08838834764831845f;
    #pragma unroll
    for (int kk = 0; kk < 4; ++kk)
        #pragma unroll
        for (int j = 0; j < 8; ++j)
            afrag[kk][j] = (short)f32_to_bf16_rne(f[kk][j] * sc);

    float w4[4];
    #pragma unroll
    for (int r = 0; r < 4; ++r) w4[r] = w[(size_t)t * H + kgrp * 4 + r];

    // ---- MFMA scores over [ks, ke), 4-tile ILP ----
    const int ntiles  = (n + 15) >> 4;
    const int ntiles4 = (ntiles + 3) & ~3;
    for (int tile = 0; tile < ntiles4; tile += 4) {
        do_tile(ks + (tile + 0) * 16, ke, ks, T, lane, col, kgrp, kr, afrag, w4, scoresL);
        do_tile(ks + (tile + 1) * 16, ke, ks, T, lane, col, kgrp, kr, afrag, w4, scoresL);
        do_tile(ks + (tile + 2) * 16, ke, ks, T, lane, col, kgrp, kr, afrag, w4, scoresL);
        do_tile(ks + (tile + 3) * 16, ke, ks, T, lane, col, kgrp, kr, afrag, w4, scoresL);
    }
    __syncthreads();

    // ---- load score bits into registers (chunks of 64) ----
    const int nch = (n + 63) >> 6;
    uint32_t ukey[NCH];
    #pragma unroll
    for (int c = 0; c < NCH; ++c) {
        if (c < nch) {
            int i = c * 64 + lane;
            ukey[c] = (i < n) ? __float_as_uint(scoresL[i]) : 0u;
        } else ukey[c] = 0u;
    }

    // ---- exact K-th value via ballot binary search on score bits ----
    const int Keff = (n < K) ? n : K;
    uint32_t ustar = 0;
    int ttake = K;                       // ties to accept (ascending index)
    if (n > K) {
        uint32_t lo = 0, hi = 0x80000000u;
        for (int it = 0; it < 31; ++it) {
            uint32_t mid = (lo + hi) >> 1;   // >= 1 always
            int cnt = 0;
            #pragma unroll
            for (int c = 0; c < NCH; ++c)
                if (c < nch) cnt += (int)__popcll(__ballot(ukey[c] >= mid));
            if (cnt >= K) lo = mid; else hi = mid;
        }
        ustar = lo;                      // K-th largest value's bits
        int cnt_gt = 0;
        #pragma unroll
        for (int c = 0; c < NCH; ++c)
            if (c < nch) cnt_gt += (int)__popcll(__ballot(ukey[c] > ustar));
        ttake = K - cnt_gt;
    }

    // ---- gather exactly Keff keys (ballot compaction; ties by ascending idx) ----
    {
        const unsigned long long ltm = (1ull << lane) - 1ull;
        int base = 0, tieBase = 0;
        const bool selAll = (n <= K);
        #pragma unroll
        for (int c = 0; c < NCH; ++c) {
            if (c < nch) {
                int i = c * 64 + lane;
                bool inb = (i < n);
                uint32_t u = ukey[c];
                bool isGt  = inb && (selAll || u > ustar);
                bool isTie = inb && !selAll && (u == ustar);
                unsigned long long mt = __ballot(isTie);
                int tr = tieBase + (int)__popcll(mt & ltm);
                bool take = isGt || (isTie && tr < ttake);
                unsigned long long m = __ballot(take);
                if (take) {
                    int pos = base + (int)__popcll(m & ltm);
                    int s = ks + i;
                    cand[pos] = ((((unsigned long long)u << 11) |
                                  (unsigned long long)(2047 - s)) + 1ull);
                }
                base    += (int)__popcll(m);
                tieBase += (int)__popcll(mt);
            }
        }
        for (int i = Keff + lane; i < SORTN; i += 64) cand[i] = 0ull;
    }
    __syncthreads();

    // ---- register bitonic sort of 256 keys, descending; e = 4*lane + r ----
    unsigned long long kreg[4];
    #pragma unroll
    for (int r = 0; r < 4; ++r) kreg[r] = cand[4 * lane + r];

    #define CX(a, b, dsc) { unsigned long long _mx = (a) > (b) ? (a) : (b); \
                            unsigned long long _mn = (a) > (b) ? (b) : (a); \
                            (a) = (dsc) ? _mx : _mn; (b) = (dsc) ? _mn : _mx; }
    #pragma unroll
    for (int size = 2; size <= SORTN; size <<= 1) {
        #pragma unroll
        for (int stride = SORTN >> 1; stride >= 4; stride >>= 1) {
            if (stride > (size >> 1)) continue;
            int lmask = stride >> 2;
            #pragma unroll
            for (int r = 0; r < 4; ++r) {
                int e = 4 * lane + r;
                unsigned long long other = __shfl_xor(kreg[r], lmask, 64);
                bool desc = ((e & size) == 0);
                bool iAmLow = ((e & stride) == 0);
                bool keepMax = (iAmLow == desc);
                kreg[r] = keepMax ? (kreg[r] > other ? kreg[r] : other)
                                  : (kreg[r] < other ? kreg[r] : other);
            }
        }
        if (size >= 4) {
            bool d = (((4 * lane) & size) == 0);
            CX(kreg[0], kreg[2], d);
            CX(kreg[1], kreg[3], d);
            CX(kreg[0], kreg[1], d);
            CX(kreg[2], kreg[3], d);
        } else {
            CX(kreg[0], kreg[1], true);
            CX(kreg[2], kreg[3], false);
        }
    }
    #undef CX

    // ---- emit (val f32, idx as float), 16B stores ----
    float4_t v4, i4;
    #pragma unroll
    for (int r = 0; r < 4; ++r) {
        int e = 4 * lane + r;
        unsigned long long key = kreg[r];
        float v; int idx;
        if (key != 0ull) {
            unsigned long long km1 = key - 1ull;
            v = __uint_as_float((uint32_t)(km1 >> 11));
            idx = 2047 - (int)(km1 & 0x7FFull);
        } else {
            int pidx = e - Keff;
            idx = (pidx < ks) ? pidx : (ke + (pidx - ks));
            v = -1e30f;
        }
        v4[r] = v; i4[r] = (float)idx;
    }
    if (4 * lane < K) {
        *(float4_t*)(out_vals + (size_t)t * K + 4 * lane) = v4;
        *(float4_t*)(out_idx  + (size_t)t * K + 4 * lane) = i4;
    }
}

extern "C" void kernel_launch(void* const* d_in, const int* in_sizes, int n_in,
                              void* d_out, int out_size, void* d_ws, size_t ws_size,
                              hipStream_t stream) {
    const unsigned short* q = (const unsigned short*)d_in[0];
    const unsigned short* k = (const unsigned short*)d_in[1];
    const float* w          = (const float*)d_in[2];
    const int* seq_lens     = (const int*)d_in[3];
    const int n_seq = in_sizes[3];
    const int T = in_sizes[1] / DDIM;
    const int H = in_sizes[2] / T;
    const int K = out_size / (2 * T);

    unsigned short* kr = (unsigned short*)d_ws;      // [T,128] rotated k
    float* out_vals = (float*)d_out;
    float* out_idx  = out_vals + (size_t)T * K;

    rotate_k_kernel<<<dim3((T + 3) / 4), dim3(256), 0, stream>>>(k, kr, T);
    indexer_main<<<dim3(T), dim3(64), 0, stream>>>(
        q, w, seq_lens, n_seq, kr, out_vals, out_idx, T, H, K);
}

// Round 4
// 126.137 us; speedup vs baseline: 1.1077x; 1.1077x over previous
//
#include <hip/hip_runtime.h>
#include <hip/hip_bf16.h>
#include <stdint.h>

typedef __attribute__((ext_vector_type(8))) short short8;
typedef __attribute__((ext_vector_type(4))) float float4_t;

#define DDIM 128
#define SORTN 256
#define NCH  16          // selection chunks of 64 -> supports n_w <= 1024
#define SCAP 1040        // per-token score capacity (input: seq_lens=[1024,1024])
#define LROW 136         // LDS row pitch in shorts (272B = 17*16B: balanced banks, 16B aligned)

__device__ inline unsigned short f32_to_bf16_rne(float f) {
    uint32_t u = __float_as_uint(f);
    return (unsigned short)((u + 0x7FFFu + ((u >> 16) & 1u)) >> 16);
}
__device__ inline float bf16_to_f32(unsigned short h) {
    return __uint_as_float(((uint32_t)h) << 16);
}

// ---- rotate k: one wave per row, FWHT-128 via registers + shfl, no LDS ----
__global__ __launch_bounds__(256) void rotate_k_kernel(
        const unsigned short* __restrict__ k, unsigned short* __restrict__ kr, int T) {
    int row = blockIdx.x * 4 + (threadIdx.x >> 6);
    if (row >= T) return;
    int lane = threadIdx.x & 63;
    ushort2 in = *(const ushort2*)(k + (size_t)row * DDIM + 2 * lane);
    float x0 = bf16_to_f32(in.x), x1 = bf16_to_f32(in.y);
    { float a = x0 + x1, b = x0 - x1; x0 = a; x1 = b; }
    #pragma unroll
    for (int m = 1; m <= 32; m <<= 1) {
        float y0 = __shfl_xor(x0, m, 64);
        float y1 = __shfl_xor(x1, m, 64);
        bool hi = (lane & m) != 0;
        x0 = hi ? (y0 - x0) : (x0 + y0);
        x1 = hi ? (y1 - x1) : (x1 + y1);
    }
    const float sc = 0.08838834764831845f;
    ushort2 o; o.x = f32_to_bf16_rne(x0 * sc); o.y = f32_to_bf16_rne(x1 * sc);
    *(ushort2*)(kr + (size_t)row * DDIM + 2 * lane) = o;
}

__device__ inline int ks_of(const int* seq_lens, int n_seq, int t) {
    int off = 0, r = 0;
    for (int i = 0; i < n_seq; ++i) {
        int nx = off + seq_lens[i];
        if (t < nx) { r = off; break; }
        off = nx;
    }
    return r;
}

// one block = 4 waves = 4 consecutive tokens; shared LDS K-staging;
// MFMA M = 4 tokens x 4 heads (4 head-group acc chains share each B-frag).
__global__ __launch_bounds__(256) void indexer_main(
        const unsigned short* __restrict__ q,   // [T,H,128] bf16 bits
        const float* __restrict__ w,            // [T,H]
        const int* __restrict__ seq_lens, int n_seq,
        const unsigned short* __restrict__ kr,  // [T,128] rotated bf16 bits
        float* __restrict__ out_vals, float* __restrict__ out_idx,
        int T, int H, int K) {
    __shared__ __align__(16) unsigned short sbuf[2][64 * LROW];  // 34816 B
    __shared__ float scw_all[4][SCAP];                           // 16640 B
    __shared__ unsigned long long cand[4][SORTN];                //  8192 B

    const int tid  = threadIdx.x;
    const int wv   = tid >> 6;
    const int lane = tid & 63;
    const int col  = lane & 15;
    const int kgrp = lane >> 4;

    const int t0  = T - 4 - 4 * (int)blockIdx.x;     // biggest tokens in block 0
    const int t_w = t0 + wv;
    const bool wvalid = (t_w >= 0) && (t_w < T);

    // per-wave window (for selection/emit)
    const int ks_w = wvalid ? ks_of(seq_lens, n_seq, t_w) : 0;
    const int ke_w = wvalid ? (t_w + 1) : 0;
    const int n_w  = ke_w - ks_w;

    // per-lane token (for score writes): token index = kgrp
    const int t_l = t0 + kgrp;
    const bool lvalid = (t_l >= 0) && (t_l < T);
    const int ks_l = lvalid ? ks_of(seq_lens, n_seq, t_l) : 0;
    const int ke_l = lvalid ? (t_l + 1) : 0;

    // block union KV range
    const int t0c = t0 < 0 ? 0 : t0;
    const int bks = ks_of(seq_lens, n_seq, t0c);
    const int bke = (t0 + 4 < T) ? (t0 + 4) : T;
    const int span = bke - bks;
    const int nchb = (span + 63) >> 6;

    // ---- issue staging of chunk 0 first (overlaps rotation VALU) ----
    const int srow = tid >> 4, sseg = tid & 15;
    short8 pre[4];
    #pragma unroll
    for (int it = 0; it < 4; ++it) {
        int gs = bks + srow + 16 * it;
        if (gs > T - 1) gs = T - 1;
        pre[it] = *(const short8*)(kr + (size_t)gs * DDIM + sseg * 8);
    }

    // ---- rotate q for 4 tokens x 16 heads into A-frags (4 head-groups) ----
    // A m-row (lane&15) = token (col>>2), head hb*4 + (col&3)
    short8 afragA[4][4];   // [head_group][kk]
    const float scl = 0.08838834764831845f;
    #pragma unroll
    for (int hb = 0; hb < 4; ++hb) {
        int tq = t0 + (col >> 2);
        if (tq < 0) tq = 0; if (tq > T - 1) tq = T - 1;
        int hq = hb * 4 + (col & 3);
        const unsigned short* qrow = q + ((size_t)tq * H + hq) * DDIM + kgrp * 8;
        float f[4][8];
        #pragma unroll
        for (int kk = 0; kk < 4; ++kk) {
            short8 v = *(const short8*)(qrow + kk * 32);
            #pragma unroll
            for (int j = 0; j < 8; ++j) f[kk][j] = bf16_to_f32((unsigned short)v[j]);
        }
        #pragma unroll
        for (int b = 1; b <= 4; b <<= 1)
            #pragma unroll
            for (int kk = 0; kk < 4; ++kk)
                #pragma unroll
                for (int j = 0; j < 8; ++j)
                    if (!(j & b)) { float a = f[kk][j], c = f[kk][j | b];
                                    f[kk][j] = a + c; f[kk][j | b] = a - c; }
        #pragma unroll
        for (int kk = 0; kk < 4; ++kk)
            #pragma unroll
            for (int j = 0; j < 8; ++j) {
                float o = __shfl_xor(f[kk][j], 16, 64);
                f[kk][j] = (kgrp & 1) ? (o - f[kk][j]) : (f[kk][j] + o);
            }
        #pragma unroll
        for (int kk = 0; kk < 4; ++kk)
            #pragma unroll
            for (int j = 0; j < 8; ++j) {
                float o = __shfl_xor(f[kk][j], 32, 64);
                f[kk][j] = (kgrp & 2) ? (o - f[kk][j]) : (f[kk][j] + o);
            }
        #pragma unroll
        for (int j = 0; j < 8; ++j) {
            { float a = f[0][j], c = f[1][j]; f[0][j] = a + c; f[1][j] = a - c; }
            { float a = f[2][j], c = f[3][j]; f[2][j] = a + c; f[3][j] = a - c; }
            { float a = f[0][j], c = f[2][j]; f[0][j] = a + c; f[2][j] = a - c; }
            { float a = f[1][j], c = f[3][j]; f[1][j] = a + c; f[3][j] = a - c; }
        }
        #pragma unroll
        for (int kk = 0; kk < 4; ++kk)
            #pragma unroll
            for (int j = 0; j < 8; ++j)
                afragA[hb][kk][j] = (short)f32_to_bf16_rne(f[kk][j] * scl);
    }

    // weights for my lane's token (kgrp): all 16 heads
    float w16[16];
    { int tqc = t_l < 0 ? 0 : (t_l > T - 1 ? T - 1 : t_l);
      const float4* wp = (const float4*)(w + (size_t)tqc * H);
      #pragma unroll
      for (int i = 0; i < 4; ++i) {
          float4 v = wp[i];
          w16[4 * i] = v.x; w16[4 * i + 1] = v.y; w16[4 * i + 2] = v.z; w16[4 * i + 3] = v.w;
      } }

    // store chunk 0
    #pragma unroll
    for (int it = 0; it < 4; ++it)
        *(short8*)(&sbuf[0][(srow + 16 * it) * LROW + sseg * 8]) = pre[it];
    __syncthreads();

    // ---- main loop: stage chunk c+1 while computing chunk c ----
    for (int c = 0; c < nchb; ++c) {
        if (c + 1 < nchb) {
            #pragma unroll
            for (int it = 0; it < 4; ++it) {
                int gs = bks + (c + 1) * 64 + srow + 16 * it;
                if (gs > T - 1) gs = T - 1;
                pre[it] = *(const short8*)(kr + (size_t)gs * DDIM + sseg * 8);
            }
        }
        // my wave's tile: rows [wv*16, wv*16+16) of this chunk
        {
            const unsigned short* sb = sbuf[c & 1];
            const int lrow = wv * 16 + col;
            const unsigned short* bbase = sb + lrow * LROW + kgrp * 8;
            float4_t a0 = {0.f,0.f,0.f,0.f}, a1 = a0, a2 = a0, a3 = a0;
            #pragma unroll
            for (int kk = 0; kk < 4; ++kk) {
                short8 bf = *(const short8*)(bbase + kk * 32);
                a0 = __builtin_amdgcn_mfma_f32_16x16x32_bf16(afragA[0][kk], bf, a0, 0, 0, 0);
                a1 = __builtin_amdgcn_mfma_f32_16x16x32_bf16(afragA[1][kk], bf, a1, 0, 0, 0);
                a2 = __builtin_amdgcn_mfma_f32_16x16x32_bf16(afragA[2][kk], bf, a2, 0, 0, 0);
                a3 = __builtin_amdgcn_mfma_f32_16x16x32_bf16(afragA[3][kk], bf, a3, 0, 0, 0);
            }
            float p = 0.f;
            #pragma unroll
            for (int r = 0; r < 4; ++r) {
                float v0 = a0[r] > 0.f ? a0[r] : 0.f;
                float v1 = a1[r] > 0.f ? a1[r] : 0.f;
                float v2 = a2[r] > 0.f ? a2[r] : 0.f;
                float v3 = a3[r] > 0.f ? a3[r] : 0.f;
                p += w16[r] * v0 + w16[4 + r] * v1 + w16[8 + r] * v2 + w16[12 + r] * v3;
            }
            int s = bks + c * 64 + wv * 16 + col;
            if (s >= ks_l && s < ke_l) scw_all[kgrp][s - ks_l] = p;
        }
        if (c + 1 < nchb) {
            #pragma unroll
            for (int it = 0; it < 4; ++it)
                *(short8*)(&sbuf[(c + 1) & 1][(srow + 16 * it) * LROW + sseg * 8]) = pre[it];
        }
        __syncthreads();
    }

    // ---- per-wave selection on its token's scores ----
    const float* scw = scw_all[wv];
    const int n = n_w;
    const int nch = (n + 63) >> 6;
    uint32_t ukey[NCH];
    #pragma unroll
    for (int c = 0; c < NCH; ++c) {
        if (c < nch) {
            int i = c * 64 + lane;
            ukey[c] = (i < n) ? __float_as_uint(scw[i]) : 0u;
        } else ukey[c] = 0u;
    }

    const int Keff = (n < K) ? n : K;
    uint32_t ustar = 0;
    int ttake = K;
    if (n > K) {
        uint32_t lo = 0, hi = 0x80000000u;
        for (int it = 0; it < 31; ++it) {
            uint32_t mid = (lo + hi) >> 1;
            int cnt = 0;
            #pragma unroll
            for (int c = 0; c < NCH; ++c)
                if (c < nch) cnt += (int)__popcll(__ballot(ukey[c] >= mid));
            if (cnt >= K) lo = mid; else hi = mid;
        }
        ustar = lo;
        int cnt_gt = 0;
        #pragma unroll
        for (int c = 0; c < NCH; ++c)
            if (c < nch) cnt_gt += (int)__popcll(__ballot(ukey[c] > ustar));
        ttake = K - cnt_gt;
    }

    {
        const unsigned long long ltm = (1ull << lane) - 1ull;
        int base = 0, tieBase = 0;
        const bool selAll = (n <= K);
        #pragma unroll
        for (int c = 0; c < NCH; ++c) {
            if (c < nch) {
                int i = c * 64 + lane;
                bool inb = (i < n);
                uint32_t u = ukey[c];
                bool isGt  = inb && (selAll || u > ustar);
                bool isTie = inb && !selAll && (u == ustar);
                unsigned long long mt = __ballot(isTie);
                int tr = tieBase + (int)__popcll(mt & ltm);
                bool take = isGt || (isTie && tr < ttake);
                unsigned long long m = __ballot(take);
                if (take) {
                    int pos = base + (int)__popcll(m & ltm);
                    int s = ks_w + i;
                    cand[wv][pos] = ((((unsigned long long)u << 11) |
                                     (unsigned long long)(2047 - s)) + 1ull);
                }
                base    += (int)__popcll(m);
                tieBase += (int)__popcll(mt);
            }
        }
        for (int i = Keff + lane; i < SORTN; i += 64) cand[wv][i] = 0ull;
    }

    // ---- register bitonic sort of 256 keys, descending; e = 4*lane + r ----
    unsigned long long kreg[4];
    #pragma unroll
    for (int r = 0; r < 4; ++r) kreg[r] = cand[wv][4 * lane + r];

    #define CX(a, b, dsc) { unsigned long long _mx = (a) > (b) ? (a) : (b); \
                            unsigned long long _mn = (a) > (b) ? (b) : (a); \
                            (a) = (dsc) ? _mx : _mn; (b) = (dsc) ? _mn : _mx; }
    #pragma unroll
    for (int size = 2; size <= SORTN; size <<= 1) {
        #pragma unroll
        for (int stride = SORTN >> 1; stride >= 4; stride >>= 1) {
            if (stride > (size >> 1)) continue;
            int lmask = stride >> 2;
            #pragma unroll
            for (int r = 0; r < 4; ++r) {
                int e = 4 * lane + r;
                unsigned long long other = __shfl_xor(kreg[r], lmask, 64);
                bool desc = ((e & size) == 0);
                bool iAmLow = ((e & stride) == 0);
                bool keepMax = (iAmLow == desc);
                kreg[r] = keepMax ? (kreg[r] > other ? kreg[r] : other)
                                  : (kreg[r] < other ? kreg[r] : other);
            }
        }
        if (size >= 4) {
            bool d = (((4 * lane) & size) == 0);
            CX(kreg[0], kreg[2], d);
            CX(kreg[1], kreg[3], d);
            CX(kreg[0], kreg[1], d);
            CX(kreg[2], kreg[3], d);
        } else {
            CX(kreg[0], kreg[1], true);
            CX(kreg[2], kreg[3], false);
        }
    }
    #undef CX

    // ---- emit ----
    if (wvalid && 4 * lane < K) {
        float4_t v4, i4;
        #pragma unroll
        for (int r = 0; r < 4; ++r) {
            int e = 4 * lane + r;
            unsigned long long key = kreg[r];
            float v; int idx;
            if (key != 0ull) {
                unsigned long long km1 = key - 1ull;
                v = __uint_as_float((uint32_t)(km1 >> 11));
                idx = 2047 - (int)(km1 & 0x7FFull);
            } else {
                int pidx = e - Keff;
                idx = (pidx < ks_w) ? pidx : (ke_w + (pidx - ks_w));
                v = -1e30f;
            }
            v4[r] = v; i4[r] = (float)idx;
        }
        *(float4_t*)(out_vals + (size_t)t_w * K + 4 * lane) = v4;
        *(float4_t*)(out_idx  + (size_t)t_w * K + 4 * lane) = i4;
    }
}

extern "C" void kernel_launch(void* const* d_in, const int* in_sizes, int n_in,
                              void* d_out, int out_size, void* d_ws, size_t ws_size,
                              hipStream_t stream) {
    const unsigned short* q = (const unsigned short*)d_in[0];
    const unsigned short* k = (const unsigned short*)d_in[1];
    const float* w          = (const float*)d_in[2];
    const int* seq_lens     = (const int*)d_in[3];
    const int n_seq = in_sizes[3];
    const int T = in_sizes[1] / DDIM;
    const int H = in_sizes[2] / T;
    const int K = out_size / (2 * T);

    unsigned short* kr = (unsigned short*)d_ws;      // [T,128] rotated k
    float* out_vals = (float*)d_out;
    float* out_idx  = out_vals + (size_t)T * K;

    rotate_k_kernel<<<dim3((T + 3) / 4), dim3(256), 0, stream>>>(k, kr, T);
    indexer_main<<<dim3((T + 3) / 4), dim3(256), 0, stream>>>(
        q, w, seq_lens, n_seq, kr, out_vals, out_idx, T, H, K);
}